// Round 14
// baseline (474.300 us; speedup 1.0000x reference)
//
#include <hip/hip_runtime.h>
#include <hip/hip_fp16.h>
#include <hip/hip_cooperative_groups.h>
#include <cstdint>
#include <cmath>

namespace cg = cooperative_groups;

// Problem constants
#define NB 2
#define NC 256
#define HW 2304          // 48*48
#define HID 64
#define OH 96
#define OW 96
#define N1 9216          // 96*96
#define SCALE_ATTN 0.17677669529663689f   // 32^-0.5
#define RESZ ((float)(47.0/95.0))

// oc-group split for k4 phase: 4 waves, counts {5,5,4,4}
__device__ __host__ inline int ocb_of(int w) { return w < 2 ? w * 5 : 10 + (w - 2) * 4; }
__device__ __host__ inline int cnt_of(int w) { return w < 2 ? 5 : 4; }

struct h4v { __half2 lo, hi; };   // 4 halves = 8B

// Single persistent cooperative kernel; phases separated by grid.sync().
// LDS union (13.2 KB): P0 tile[32][33] | P1 xs[4][256] | P3 ts[100*33] | P4 wts/cof/outb.
__global__ __launch_bounds__(256) void mega(
    const float* __restrict__ x, const float* __restrict__ ln_g,
    const float* __restrict__ ln_b, const float* __restrict__ Wq,
    const float* __restrict__ Wk, const float* __restrict__ dw_w,
    const float* __restrict__ og, const float* __restrict__ ob,
    const float* __restrict__ off_w, const float* __restrict__ off_b,
    const float* __restrict__ rpb, float* __restrict__ out,
    float* __restrict__ WT4, float* __restrict__ q_pix, float* __restrict__ pred,
    float* __restrict__ dwT, float* __restrict__ wg, float* __restrict__ bsg,
    __half* __restrict__ v_nhwc, __half* __restrict__ k_nhwc,
    __half* __restrict__ tbuf_h)
{
    cg::grid_group grid = cg::this_grid();
    __shared__ __align__(16) float lds[3300];
    int tid = threadIdx.x;

    // ================= P0: prep (v transpose + weight relayouts) =================
    for (int vb = blockIdx.x; vb < 1304; vb += gridDim.x) {
        if (vb < 1152) {
            float (*tile)[33] = (float(*)[33])lds;
            int pt = vb % 72;
            int t2 = vb / 72;
            int ct = t2 & 3, bg = t2 >> 2;
            int b = bg >> 1, g = bg & 1;
            int tx = tid & 31, row = tid >> 5;
#pragma unroll
            for (int r = 0; r < 4; r++) {
                int c = ct * 32 + row + r * 8;
                tile[row + r * 8][tx] = x[((size_t)(b * 256 + g * 128 + c)) * HW + pt * 32 + tx];
            }
            __syncthreads();
#pragma unroll
            for (int r = 0; r < 4; r++) {
                int p = pt * 32 + row + r * 8;
                v_nhwc[((size_t)bg * HW + p) * 128 + ct * 32 + tx] =
                    __float2half(tile[tx][row + r * 8]);
            }
            __syncthreads();
        } else {
            int idx = (vb - 1152) * 256 + tid;
            if (idx < 32768) {
                int c = idx >> 7, t = idx & 127;
                float v = (t < 64) ? Wq[t * 256 + c] : Wk[(t - 64) * 256 + c];
                WT4[(((size_t)(c >> 2) * 128) + t) * 4 + (c & 3)] = v;
            } else if (idx < 32768 + 288) {
                int i = idx - 32768;
                dwT[i] = dw_w[(i & 31) * 9 + (i >> 5)];
            } else if (idx < 32768 + 288 + 5760) {
                int i = idx - 32768 - 288;
                int w = i / 1440, r = i - w * 1440;
                int kk = r / 5, j = r - kk * 5;
                wg[i] = (j < cnt_of(w)) ? off_w[(ocb_of(w) + j) * 288 + kk] : 0.f;
            } else if (idx < 32768 + 288 + 5760 + 20) {
                int i = idx - 32768 - 288 - 5760;
                int w = i / 5, j = i - w * 5;
                bsg[i] = (j < cnt_of(w)) ? off_b[ocb_of(w) + j] : 0.f;
            }
        }
    }
    grid.sync();

    // ================= P1: channel LN(256) + Q/K projection (4 px/vblock) ========
    {
        float (*xs)[256] = (float(*)[256])lds;
        int wv = tid >> 6, lane = tid & 63;
        for (int vb = blockIdx.x; vb < 1152; vb += gridDim.x) {
            {
                int pix = vb * 4 + wv;
                int b = pix / HW, p = pix - b * HW;
                int c0 = lane * 2;
                __half2 h0 = *(const __half2*)(v_nhwc + (((size_t)(b * 2 + 0) * HW) + p) * 128 + c0);
                __half2 h1 = *(const __half2*)(v_nhwc + (((size_t)(b * 2 + 1) * HW) + p) * 128 + c0);
                float2 u0 = __half22float2(h0);
                float2 u1 = __half22float2(h1);
                float s = u0.x + u0.y + u1.x + u1.y;
#pragma unroll
                for (int off = 1; off < 64; off <<= 1) s += __shfl_xor(s, off);
                float mu = s * (1.f / 256.f);
                float d0 = u0.x - mu, d1 = u0.y - mu, d2 = u1.x - mu, d3 = u1.y - mu;
                float q = d0 * d0 + d1 * d1 + d2 * d2 + d3 * d3;
#pragma unroll
                for (int off = 1; off < 64; off <<= 1) q += __shfl_xor(q, off);
                float rs = rsqrtf(q * (1.f / 256.f) + 1e-5f);
                float2 w0, w1;
                w0.x = d0 * rs * ln_g[c0] + ln_b[c0];
                w0.y = d1 * rs * ln_g[c0 + 1] + ln_b[c0 + 1];
                w1.x = d2 * rs * ln_g[128 + c0] + ln_b[128 + c0];
                w1.y = d3 * rs * ln_g[129 + c0] + ln_b[129 + c0];
                *(float2*)&xs[wv][c0] = w0;
                *(float2*)&xs[wv][128 + c0] = w1;
            }
            __syncthreads();
            int o = tid & 127, ph = tid >> 7;
            float a0 = 0.f, a1 = 0.f;
            const float4* wp = (const float4*)WT4 + o;
            const float4* xa = (const float4*)xs[ph * 2];
            const float4* xb4 = (const float4*)xs[ph * 2 + 1];
#pragma unroll 8
            for (int c4 = 0; c4 < 64; c4++) {
                float4 w = wp[(size_t)c4 * 128];
                float4 p0 = xa[c4], p1 = xb4[c4];
                a0 += w.x * p0.x + w.y * p0.y + w.z * p0.z + w.w * p0.w;
                a1 += w.x * p1.x + w.y * p1.y + w.z * p1.z + w.w * p1.w;
            }
#pragma unroll
            for (int k = 0; k < 2; k++) {
                int pix = vb * 4 + ph * 2 + k;
                int b = pix / HW, p = pix - b * HW;
                float a = k ? a1 : a0;
                if (o < 64) {
                    q_pix[(((size_t)b * HW) + p) * 64 + o] = a;
                } else {
                    int t = o - 64, g = t >> 5, c32 = t & 31;
                    k_nhwc[(((size_t)(b * 2 + g) * HW) + p) * 32 + c32] = __float2half(a);
                }
            }
            __syncthreads();
        }
    }
    grid.sync();

    // ================= P2: t = GELU(LN(dw3x3(resize(q)))), thread/(bg,px,ch) =====
    for (int gid = blockIdx.x * 256 + tid; gid < 4 * N1 * 32; gid += gridDim.x * 256) {
        int c = gid & 31;
        int p2 = gid >> 5;
        int bg = p2 / N1, p = p2 - bg * N1;
        int b = bg >> 1, g = bg & 1;
        int oy = p / OW, ox = p - oy * OW;
        const float* qb = q_pix + ((size_t)b * HW) * 64 + g * 32 + c;
        float acc = 0.f;
#pragma unroll
        for (int dy = -1; dy <= 1; dy++) {
            int yy = oy + dy;
            if ((unsigned)yy >= (unsigned)OH) continue;
            float ysf = yy * RESZ;
            int y0 = min((int)ysf, 46);
            float wy = ysf - (float)y0;
#pragma unroll
            for (int dx = -1; dx <= 1; dx++) {
                int xx = ox + dx;
                if ((unsigned)xx >= (unsigned)OW) continue;
                float xsf = xx * RESZ;
                int x0 = min((int)xsf, 46);
                float wx = xsf - (float)x0;
                int i00 = (y0 * 48 + x0) * 64;
                float q00 = qb[i00], q01 = qb[i00 + 64];
                float q10 = qb[i00 + 48 * 64], q11 = qb[i00 + 49 * 64];
                float qv = (q00 * (1.f - wy) + q10 * wy) * (1.f - wx)
                         + (q01 * (1.f - wy) + q11 * wy) * wx;
                acc += qv * dwT[((dy + 1) * 3 + dx + 1) * 32 + c];
            }
        }
        float s = acc;
#pragma unroll
        for (int off = 1; off < 32; off <<= 1) s += __shfl_xor(s, off);
        float mu = s * (1.f / 32.f);
        float d = acc - mu;
        float v = d * d;
#pragma unroll
        for (int off = 1; off < 32; off <<= 1) v += __shfl_xor(v, off);
        float rsv = rsqrtf(v * (1.f / 32.f) + 1e-5f);
        float t = d * rsv * og[c] + ob[c];
        float ge = 0.5f * t * (1.f + erff(t * 0.70710678118654752f));
        tbuf_h[(size_t)p2 * 32 + c] = __float2half(ge);
    }
    grid.sync();

    // ================= P3: conv 3x3 32->18 + bias (8x8 tiles, oc{5,5,4,4}) =======
    {
        float* ts = lds;   // [100][33]
        const int kof[9] = {0, 33, 66, 330, 363, 396, 660, 693, 726};
        int w = __builtin_amdgcn_readfirstlane(tid >> 6);
        int lane = tid & 63;
        int y = lane >> 3, xq = lane & 7;
        int ocb = ocb_of(w), cnt = cnt_of(w);
        for (int vb = blockIdx.x; vb < 576; vb += gridDim.x) {
            int bg = vb / 144, tile4 = vb - bg * 144;
            int ty0 = (tile4 / 12) * 8, tx0 = (tile4 % 12) * 8;
            const __half* tb = tbuf_h + (size_t)bg * N1 * 32;
            for (int item = tid; item < 400; item += 256) {
                int pt = item >> 2, qg = item & 3;       // 8 channels per item
                int hy = ty0 + pt / 10 - 1;
                int hx = tx0 + pt % 10 - 1;
                float4 raw = make_float4(0.f, 0.f, 0.f, 0.f);
                if ((unsigned)hy < (unsigned)OH && (unsigned)hx < (unsigned)OW)
                    raw = *(const float4*)(tb + ((size_t)(hy * OW + hx)) * 32 + qg * 8);
                const __half2* h2 = (const __half2*)&raw;
                int base = pt * 33 + qg * 8;
#pragma unroll
                for (int i = 0; i < 4; i++) {
                    float2 f = __half22float2(h2[i]);
                    ts[base + i * 2] = f.x;
                    ts[base + i * 2 + 1] = f.y;
                }
            }
            __syncthreads();
            float acc[5];
#pragma unroll
            for (int j = 0; j < 5; j++) acc[j] = bsg[w * 5 + j];
            const float* tsb = &ts[(y * 10 + xq) * 33];
            const float* wgp = wg + (size_t)w * 1440;
            for (int ic = 0; ic < 32; ic++) {
#pragma unroll
                for (int k = 0; k < 9; k++) {
                    float tv = tsb[kof[k] + ic];
                    const float* wr = wgp + (ic * 9 + k) * 5;
#pragma unroll
                    for (int j = 0; j < 5; j++) acc[j] += tv * wr[j];
                }
            }
            int p = (ty0 + y) * OW + tx0 + xq;
            float* pp = pred + ((size_t)bg * N1 + p) * 18 + ocb;
#pragma unroll
            for (int j = 0; j < 5; j++)
                if (j < cnt) pp[j] = acc[j];
            __syncthreads();
        }
    }
    grid.sync();

    // ================= P4: deformable attention (2 px/wave, 8 px/vblock) =========
    {
        float4 (*wts)[2][9] = (float4(*)[2][9])lds;             // 288 floats
        int4   (*cof)[2][9] = (int4(*)[2][9])(lds + 288);       // 288 floats
        float  (*outb)[2][128] = (float(*)[2][128])(lds + 576); // 1024 floats
        int wv = __builtin_amdgcn_readfirstlane(tid >> 6);
        int lane = tid & 63;
        int c = lane & 31, h = lane >> 5;
        int c4 = (lane & 31) * 4;

        for (int vb = blockIdx.x; vb < 4608; vb += gridDim.x) {
            int gp = vb * 8;
            int bg = gp / N1, p0 = gp % N1;
            int b = bg >> 1, g = bg & 1;
            int pw = p0 + wv * 2;
            int oy = pw / OW, ox0 = pw % OW;

            if (lane < 18) {
                int px = lane / 9, j = lane % 9;
                int p = pw + px;
                int ky = j / 3, kx = j % 3;
                const float* pp = pred + ((size_t)bg * N1 + p) * 18;
                float pr0 = pp[j * 2];
                float pr1 = pp[j * 2 + 1];
                float th0 = 1.f - 2.f * __builtin_amdgcn_rcpf(__expf(2.f * pr0) + 1.f);
                float th1 = 1.f - 2.f * __builtin_amdgcn_rcpf(__expf(2.f * pr1) + 1.f);
                float py  = th0 * 11.0f + (float)(ky - 1) + (float)oy;
                float pxc = th1 * 11.0f + (float)(kx - 1) + (float)(ox0 + px);
                float iy = py * RESZ, ix = pxc * RESZ;
                float y0f = floorf(iy), x0f = floorf(ix);
                float wy = iy - y0f, wx = ix - x0f;
                int y0 = (int)y0f, x0 = (int)x0f;
                bool vy0 = (unsigned)y0 < 48u, vy1 = (unsigned)(y0 + 1) < 48u;
                bool vx0 = (unsigned)x0 < 48u, vx1 = (unsigned)(x0 + 1) < 48u;
                int y0c = min(max(y0, 0), 47), y1c = min(max(y0 + 1, 0), 47);
                int x0c = min(max(x0, 0), 47), x1c = min(max(x0 + 1, 0), 47);
                float4 w;
                w.x = (vy0 && vx0) ? (1.f - wy) * (1.f - wx) : 0.f;
                w.y = (vy0 && vx1) ? (1.f - wy) * wx : 0.f;
                w.z = (vy1 && vx0) ? wy * (1.f - wx) : 0.f;
                w.w = (vy1 && vx1) ? wy * wx : 0.f;
                wts[wv][px][j] = w;
                cof[wv][px][j] = make_int4(y0c * 48 + x0c, y0c * 48 + x1c,
                                           y1c * 48 + x0c, y1c * 48 + x1c);
            }
            __syncthreads();

            const __half* kb = k_nhwc + (size_t)bg * HW * 32;
            const float* rb = rpb + (size_t)g * 288;
            const float* qb = q_pix + (size_t)b * HW * 64 + g * 32 + c;
            const __half* vbp = v_nhwc + (size_t)bg * HW * 128 + c4;

            float ysf = oy * RESZ;
            int qy0 = min((int)ysf, 46);
            float qwy = ysf - (float)qy0;

            float rv[5];
#pragma unroll
            for (int jj = 0; jj < 5; jj++) {
                int j = jj * 2 + h;
                rv[jj] = (j < 9) ? rb[j * 32 + c] : 0.f;
            }

            float qv[2];
#pragma unroll
            for (int px = 0; px < 2; px++) {
                float xsf = (ox0 + px) * RESZ;
                int qx0 = min((int)xsf, 46);
                float qwx = xsf - (float)qx0;
                int qi = (qy0 * 48 + qx0) * 64;
                float q00 = qb[qi], q01 = qb[qi + 64];
                float q10 = qb[qi + 48 * 64], q11 = qb[qi + 49 * 64];
                qv[px] = ((q00 * (1.f - qwy) + q10 * qwy) * (1.f - qwx)
                        + (q01 * (1.f - qwy) + q11 * qwy) * qwx) * SCALE_ATTN;
            }

            float s[2][5];
#pragma unroll
            for (int px = 0; px < 2; px++) {
#pragma unroll
                for (int jj = 0; jj < 5; jj++) {
                    int j = jj * 2 + h;
                    float partial = 0.f;
                    if (j < 9) {
                        float4 w = wts[wv][px][j];
                        int4 co = cof[wv][px][j];
                        float kv = w.x * __half2float(kb[co.x * 32 + c])
                                 + w.y * __half2float(kb[co.y * 32 + c])
                                 + w.z * __half2float(kb[co.z * 32 + c])
                                 + w.w * __half2float(kb[co.w * 32 + c]);
                        partial = qv[px] * (kv + rv[jj]);
                    }
#pragma unroll
                    for (int off = 1; off < 32; off <<= 1) partial += __shfl_xor(partial, off);
                    s[px][jj] = (j < 9) ? partial : -1e30f;
                }
            }

#pragma unroll
            for (int px = 0; px < 2; px++) {
                float m = s[px][0];
#pragma unroll
                for (int jj = 1; jj < 5; jj++) m = fmaxf(m, s[px][jj]);
                m = fmaxf(m, __shfl_xor(m, 32));
                float e[5];
                float sum = 0.f;
#pragma unroll
                for (int jj = 0; jj < 5; jj++) { e[jj] = __expf(s[px][jj] - m); sum += e[jj]; }
                sum += __shfl_xor(sum, 32);
                float inv = __builtin_amdgcn_rcpf(sum);
#pragma unroll
                for (int jj = 0; jj < 5; jj++) s[px][jj] = e[jj] * inv;
            }

            __half2 ac0[2], ac1[2];
#pragma unroll
            for (int px = 0; px < 2; px++) {
                ac0[px] = __float2half2_rn(0.f);
                ac1[px] = __float2half2_rn(0.f);
            }
#pragma unroll
            for (int px = 0; px < 2; px++) {
#pragma unroll
                for (int jj = 0; jj < 5; jj++) {
                    int j = jj * 2 + h;
                    if (j < 9) {
                        float pj = s[px][jj];
                        float4 w = wts[wv][px][j];
                        int4 co = cof[wv][px][j];
                        h4v a0 = *(const h4v*)(vbp + (size_t)co.x * 128);
                        h4v a1 = *(const h4v*)(vbp + (size_t)co.y * 128);
                        h4v a2 = *(const h4v*)(vbp + (size_t)co.z * 128);
                        h4v a3 = *(const h4v*)(vbp + (size_t)co.w * 128);
                        __half2 f0 = __float2half2_rn(w.x * pj);
                        __half2 f1 = __float2half2_rn(w.y * pj);
                        __half2 f2 = __float2half2_rn(w.z * pj);
                        __half2 f3 = __float2half2_rn(w.w * pj);
                        ac0[px] = __hfma2(f0, a0.lo, ac0[px]);
                        ac1[px] = __hfma2(f0, a0.hi, ac1[px]);
                        ac0[px] = __hfma2(f1, a1.lo, ac0[px]);
                        ac1[px] = __hfma2(f1, a1.hi, ac1[px]);
                        ac0[px] = __hfma2(f2, a2.lo, ac0[px]);
                        ac1[px] = __hfma2(f2, a2.hi, ac1[px]);
                        ac0[px] = __hfma2(f3, a3.lo, ac0[px]);
                        ac1[px] = __hfma2(f3, a3.hi, ac1[px]);
                    }
                }
            }
#pragma unroll
            for (int px = 0; px < 2; px++) {
                float2 lo = __half22float2(ac0[px]);
                float2 hi = __half22float2(ac1[px]);
                float4 acc = make_float4(lo.x, lo.y, hi.x, hi.y);
                acc.x += __shfl_xor(acc.x, 32);
                acc.y += __shfl_xor(acc.y, 32);
                acc.z += __shfl_xor(acc.z, 32);
                acc.w += __shfl_xor(acc.w, 32);
                if (lane < 32) *(float4*)&outb[wv][px][c4] = acc;
            }
            __syncthreads();

            {
                int ch = tid & 127, qh = tid >> 7;
                float* op = out + ((size_t)b * NC + g * 128 + ch) * N1 + p0 + qh * 4;
                float4 v4 = make_float4(outb[qh * 2][0][ch], outb[qh * 2][1][ch],
                                        outb[qh * 2 + 1][0][ch], outb[qh * 2 + 1][1][ch]);
                *(float4*)op = v4;
            }
            // next-iteration tap setup writes wts/cof (disjoint from outb); its
            // __syncthreads guarantees all final-write reads completed. Safe.
        }
    }
}

extern "C" void kernel_launch(void* const* d_in, const int* in_sizes, int n_in,
                              void* d_out, int out_size, void* d_ws, size_t ws_size,
                              hipStream_t stream) {
    const float* x      = (const float*)d_in[0];
    const float* ln_g   = (const float*)d_in[1];
    const float* ln_b   = (const float*)d_in[2];
    const float* Wq     = (const float*)d_in[3];
    const float* Wk     = (const float*)d_in[4];
    const float* dw_w   = (const float*)d_in[5];
    const float* off_g  = (const float*)d_in[6];
    const float* off_bt = (const float*)d_in[7];
    const float* off_w  = (const float*)d_in[8];
    const float* off_b  = (const float*)d_in[9];
    const float* rpb    = (const float*)d_in[10];
    float* out = (float*)d_out;

    // Workspace layout. fp32 region then fp16 region. Total ≈ 9.30 MB. NO aliasing.
    float* ws = (float*)d_ws;
    float* WT4    = ws;                       // 32768   [64][128][4]
    float* q_pix  = WT4 + 32768;              // 294912  [2][2304][64]
    float* pred   = q_pix + 294912;           // 663552  [4][9216][18]
    float* dwT    = pred + 663552;            // 288     [9][32]
    float* wg     = dwT + 288;                // 5760    [4][288][5]
    float* bsg    = wg + 5760;                // 20      [4][5]
    __half* v_nhwc = (__half*)(bsg + 20);     // 1179648 h [4][2304][128]
    __half* k_nhwc = v_nhwc + 1179648;        // 294912 h  [4][2304][32]
    __half* tbuf_h = k_nhwc + 294912;         // 1179648 h [4][9216][32]

    // Cooperative grid sizing: blocks/CU from occupancy API x 256 CUs (MI355X).
    int nbpc = 0;
    (void)hipOccupancyMaxActiveBlocksPerMultiprocessor(&nbpc, (const void*)mega, 256, 0);
    if (nbpc < 1) nbpc = 1;
    long long gridl = (long long)nbpc * 256;
    if (gridl > 4608) gridl = 4608;
    dim3 gridDim((unsigned)gridl), blockDim(256);

    void* args[] = {
        (void*)&x, (void*)&ln_g, (void*)&ln_b, (void*)&Wq, (void*)&Wk,
        (void*)&dw_w, (void*)&off_g, (void*)&off_bt, (void*)&off_w, (void*)&off_b,
        (void*)&rpb, (void*)&out,
        (void*)&WT4, (void*)&q_pix, (void*)&pred, (void*)&dwT, (void*)&wg,
        (void*)&bsg, (void*)&v_nhwc, (void*)&k_nhwc, (void*)&tbuf_h
    };
    (void)hipLaunchCooperativeKernel((const void*)mega, gridDim, blockDim,
                                     args, 0, stream);
}